// Round 8
// baseline (21.338 us; speedup 1.0000x reference)
//
#include <hip/hip_runtime.h>

// out[b,i,h] = m_i * (1/denom_b) * sum_{j valid} sigmoid(zc[b,i,h] + zy[b,j,h])
// zc = z@Wc^T+bc, zy = z@Wy^T+by.
// sigmoid(a+b) = 1/(1+e^{-a}e^{-b}); E=e^{-zc} (regs), F=e^{-zy} (LDS).
// LDS-PIPE MINIMIZATION (the measured wall): previous versions issued ~96 LDS
// instrs/wave (~6.7 us serialized per CU). Now:
//   - stage A reads z and W straight from global (half-wave-broadcast
//     addresses, L1-resident: 20 KB/CU working set) -> 0 LDS instrs, no
//     staging writes, one barrier instead of two.
//   - F stored TRANSPOSED F_t[h][j] (row stride 52 floats, rows 16B-aligned)
//     -> stage B reads 12 x ds_read_b128 per thread (was 48 x ds_read_b32).
// Invalid j: F=1e8 sentinel -> contribution ~1e-8; fixed 12-quad unrolled loop.
// 4-way rational: 1/t0+..+1/t3 = (sum triple prods)/(t0t1t2t3) -> 1 rcp/4j/row,
// rows packed in v2f (v_pk_fma_f32).

#define LOG2E 1.4426950408889634f

typedef float v2f __attribute__((ext_vector_type(2)));

constexpr int NV = 48;
constexpr int H  = 32;
constexpr int BLOCK = 768;        // 12 waves; thread = (i0 in 0..23, h in 0..31)
constexpr int FSTRIDE = 52;       // F_t row stride: %4==0 (16B-aligned b128),
                                  // 4-way bank conflict (best for 32 rows)
constexpr float F_INV = 1.0e8f;   // sentinel for invalid j

__global__ __launch_bounds__(BLOCK, 6)
void OptLinker_attn_kernel(const float* __restrict__ z,
                           const float* __restrict__ Wc,
                           const float* __restrict__ bc,
                           const float* __restrict__ Wy,
                           const float* __restrict__ by,
                           const int*   __restrict__ mask,
                           float* __restrict__ out)
{
    __shared__ float F_t[H * FSTRIDE];   // 6656 B, transposed: [h][j]

    const int b   = blockIdx.x;
    const int tid = threadIdx.x;
    const int h   = tid & 31;            // lane's H column
    const int i0  = tid >> 5;            // 0..23; rows i0, i0+24
    const int r0  = i0, r1 = i0 + 24;
    const int lane = tid & 63;

    // ---- mask ballot + biases (issue early, longest dep chain) ----
    const int mv = (lane < NV) ? mask[b * NV + lane] : 0;
    const float bcv = bc[h], byv = by[h];

    const float4* zr0 = (const float4*)(z + (size_t)b * (NV * H) + r0 * H);
    const float4* zr1 = (const float4*)(z + (size_t)b * (NV * H) + r1 * H);
    const float4* wcr = (const float4*)(Wc + h * H);   // row h of Wc
    const float4* wyr = (const float4*)(Wy + h * H);   // row h of Wy

    const unsigned long long bits = __ballot(mv != 0);

    // ---- stage A: dual-row matvec, streaming W and z from global ----
    // (all addresses identical within each half-wave -> broadcast loads)
    auto matvec2 = [&](const float4* __restrict__ wr, float bias,
                       float& o0, float& o1) {
        v2f a0 = {0.f, 0.f}, a1 = {0.f, 0.f};
        #pragma unroll
        for (int q = 0; q < 8; ++q) {
            const float4 wq = wr[q];
            const float4 x0 = zr0[q];
            const float4 x1 = zr1[q];
            const v2f wlo = {wq.x, wq.y}, whi = {wq.z, wq.w};
            a0 = __builtin_elementwise_fma((v2f){x0.x, x0.y}, wlo, a0);
            a0 = __builtin_elementwise_fma((v2f){x0.z, x0.w}, whi, a0);
            a1 = __builtin_elementwise_fma((v2f){x1.x, x1.y}, wlo, a1);
            a1 = __builtin_elementwise_fma((v2f){x1.z, x1.w}, whi, a1);
        }
        o0 = a0.x + a0.y + bias;
        o1 = a1.x + a1.y + bias;
    };

    float c0, c1, y0, y1;
    matvec2(wcr, bcv, c0, c1);           // zc rows
    matvec2(wyr, byv, y0, y1);           // zy rows

    const float E0 = __builtin_amdgcn_exp2f(-c0 * LOG2E);   // e^{-zc}
    const float E1 = __builtin_amdgcn_exp2f(-c1 * LOG2E);
    F_t[h * FSTRIDE + r0] = ((bits >> r0) & 1ull)
        ? __builtin_amdgcn_exp2f(-y0 * LOG2E) : F_INV;      // e^{-zy}
    F_t[h * FSTRIDE + r1] = ((bits >> r1) & 1ull)
        ? __builtin_amdgcn_exp2f(-y1 * LOG2E) : F_INV;

    __syncthreads();   // F_t ready (single barrier in the whole kernel)

    // ---- stage B: 12 x ds_read_b128 from own row h, packed rational ----
    const v2f E2  = {E0, E1};
    const v2f one = {1.f, 1.f};
    v2f acc2 = {0.f, 0.f};
    const float4* frow = (const float4*)(F_t + h * FSTRIDE);
    #pragma unroll
    for (int jq = 0; jq < NV / 4; ++jq) {
        const float4 f = frow[jq];       // 4 F values in one LDS instr
        const v2f t0 = __builtin_elementwise_fma(E2, (v2f){f.x, f.x}, one);
        const v2f t1 = __builtin_elementwise_fma(E2, (v2f){f.y, f.y}, one);
        const v2f t2 = __builtin_elementwise_fma(E2, (v2f){f.z, f.z}, one);
        const v2f t3 = __builtin_elementwise_fma(E2, (v2f){f.w, f.w}, one);
        const v2f p01 = t0 * t1, p23 = t2 * t3;
        const v2f num = __builtin_elementwise_fma(t0 + t1, p23, (t2 + t3) * p01);
        const v2f den = p01 * p23;
        v2f r;
        r.x = __builtin_amdgcn_rcpf(den.x);
        r.y = __builtin_amdgcn_rcpf(den.y);
        acc2 = __builtin_elementwise_fma(num, r, acc2);
    }

    // ---- epilogue (wave writes rows 2w,2w+1 -> 256B contiguous) ----
    const int nvalid = __popcll(bits);
    const float rden = __builtin_amdgcn_rcpf((float)nvalid);
    float* ob = out + (size_t)b * (NV * H);
    ob[r0 * H + h] = ((bits >> r0) & 1ull) ? acc2.x * rden : 0.0f;
    ob[r1 * H + h] = ((bits >> r1) & 1ull) ? acc2.y * rden : 0.0f;
}

extern "C" void kernel_launch(void* const* d_in, const int* in_sizes, int n_in,
                              void* d_out, int out_size, void* d_ws, size_t ws_size,
                              hipStream_t stream) {
    const float* z    = (const float*)d_in[0];
    const float* Wc   = (const float*)d_in[1];
    const float* bc   = (const float*)d_in[2];
    const float* Wy   = (const float*)d_in[3];
    const float* by   = (const float*)d_in[4];
    const int*   mask = (const int*)d_in[5];
    float* out = (float*)d_out;

    const int ngraph = in_sizes[0] / (NV * H);   // 512
    OptLinker_attn_kernel<<<ngraph, BLOCK, 0, stream>>>(z, Wc, bc, Wy, by, mask, out);
}

// Round 9
// 11.561 us; speedup vs baseline: 1.8457x; 1.8457x over previous
//
#include <hip/hip_runtime.h>

// out[b,i,h] = m_i * (1/denom_b) * sum_{j valid} sigmoid(zc[b,i,h] + zy[b,j,h])
// zc = z@Wc^T+bc, zy = z@Wy^T+by.
// sigmoid(a+b) = 1/(1+e^{-a}e^{-b}); E=e^{-zc} (regs), F=e^{-zy} (LDS).
// LDS-pipe is the measured wall (~8.5us/CU in round 7). This version:
//   - W: coalesced global->LDS staging, per-lane row gather via ds_read_b128
//     (the correct pipe for a row gather; global gather was 32 cache lines
//     per instr -> 21us in round 8).
//   - z: DIRECT from global. Addresses are half-wave-uniform -> 2x16B per
//     wave-instr, L1-resident (12KB/CU). Zero LDS traffic for z (was 4.6k
//     cyc/block), no z staging writes, one less barrier dependency.
//   - F: TRANSPOSED F_t[h][j], row stride 52 -> stage B = 12 ds_read_b128
//     per thread (was 48 ds_read_b32).
// Invalid j: F=1e8 sentinel -> contribution ~1e-8; fixed 12-quad unrolled loop.
// 4-way rational: 1/t0+..+1/t3 = (sum triple prods)/(t0t1t2t3) -> 1 rcp/4j/row,
// rows packed in v2f (v_pk_fma_f32). Two-pass stage A keeps VGPR <= ~60.

#define LOG2E 1.4426950408889634f

typedef float v2f __attribute__((ext_vector_type(2)));

constexpr int NV = 48;
constexpr int H  = 32;
constexpr int BLOCK = 768;        // 12 waves; thread = (i0 in 0..23, h in 0..31)
constexpr int WPAD = 36;          // W row stride (floats): 16B-aligned, 4-way
constexpr int FSTRIDE = 52;       // F_t row stride: 16B-aligned b128 rows
constexpr float F_INV = 1.0e8f;   // sentinel for invalid j

__global__ __launch_bounds__(BLOCK, 6)
void OptLinker_attn_kernel(const float* __restrict__ z,
                           const float* __restrict__ Wc,
                           const float* __restrict__ bc,
                           const float* __restrict__ Wy,
                           const float* __restrict__ by,
                           const int*   __restrict__ mask,
                           float* __restrict__ out)
{
    __shared__ float wc_s[H * WPAD];     // 4.5 KB
    __shared__ float wy_s[H * WPAD];     // 4.5 KB
    __shared__ float F_t[H * FSTRIDE];   // 6.5 KB transposed: [h][j]

    const int b   = blockIdx.x;
    const int tid = threadIdx.x;
    const int h   = tid & 31;            // lane's H column
    const int i0  = tid >> 5;            // 0..23; rows i0, i0+24
    const int r0  = i0, r1 = i0 + 24;
    const int lane = tid & 63;

    // ---- mask ballot + biases (issue early) ----
    const int mv = (lane < NV) ? mask[b * NV + lane] : 0;
    const float bcv = bc[h], byv = by[h];

    // ---- W -> LDS, coalesced, one float4 per thread (tid<512) ----
    if (tid < 512) {
        const int q = tid & 255;                    // float4 index within matrix
        const float4 v = (tid < 256) ? ((const float4*)Wc)[q]
                                     : ((const float4*)Wy)[q];
        float* dst = (tid < 256 ? wc_s : wy_s) + (q >> 3) * WPAD + (q & 7) * 4;
        *(float4*)dst = v;                          // 16B-aligned
    }

    const unsigned long long bits = __ballot(mv != 0);

    // z row pointers: half-wave-uniform addresses -> broadcast global loads
    const float4* zr0 = (const float4*)(z + (size_t)b * (NV * H) + r0 * H);
    const float4* zr1 = (const float4*)(z + (size_t)b * (NV * H) + r1 * H);

    __syncthreads();   // W staged

    // ---- stage A pass 1 (Wc): W row in regs, z streamed from global ----
    float E0, E1;
    {
        float4 w[8];
        const float* wr = wc_s + h * WPAD;
        #pragma unroll
        for (int q = 0; q < 8; ++q) w[q] = *(const float4*)(wr + q * 4);
        v2f a0 = {0.f, 0.f}, a1 = {0.f, 0.f};
        #pragma unroll
        for (int q = 0; q < 8; ++q) {
            const float4 x0 = zr0[q], x1 = zr1[q];   // L1/HBM, 2x16B per instr
            const v2f wlo = {w[q].x, w[q].y}, whi = {w[q].z, w[q].w};
            a0 = __builtin_elementwise_fma((v2f){x0.x, x0.y}, wlo, a0);
            a0 = __builtin_elementwise_fma((v2f){x0.z, x0.w}, whi, a0);
            a1 = __builtin_elementwise_fma((v2f){x1.x, x1.y}, wlo, a1);
            a1 = __builtin_elementwise_fma((v2f){x1.z, x1.w}, whi, a1);
        }
        E0 = __builtin_amdgcn_exp2f(-(a0.x + a0.y + bcv) * LOG2E);  // e^{-zc}
        E1 = __builtin_amdgcn_exp2f(-(a1.x + a1.y + bcv) * LOG2E);
    }

    // ---- stage A pass 2 (Wy): z re-read from L1 (12KB/CU resident) ----
    {
        float4 w[8];
        const float* wr = wy_s + h * WPAD;
        #pragma unroll
        for (int q = 0; q < 8; ++q) w[q] = *(const float4*)(wr + q * 4);
        v2f a0 = {0.f, 0.f}, a1 = {0.f, 0.f};
        #pragma unroll
        for (int q = 0; q < 8; ++q) {
            const float4 x0 = zr0[q], x1 = zr1[q];
            const v2f wlo = {w[q].x, w[q].y}, whi = {w[q].z, w[q].w};
            a0 = __builtin_elementwise_fma((v2f){x0.x, x0.y}, wlo, a0);
            a0 = __builtin_elementwise_fma((v2f){x0.z, x0.w}, whi, a0);
            a1 = __builtin_elementwise_fma((v2f){x1.x, x1.y}, wlo, a1);
            a1 = __builtin_elementwise_fma((v2f){x1.z, x1.w}, whi, a1);
        }
        F_t[h * FSTRIDE + r0] = ((bits >> r0) & 1ull)
            ? __builtin_amdgcn_exp2f(-(a0.x + a0.y + byv) * LOG2E) : F_INV;
        F_t[h * FSTRIDE + r1] = ((bits >> r1) & 1ull)
            ? __builtin_amdgcn_exp2f(-(a1.x + a1.y + byv) * LOG2E) : F_INV;
    }

    __syncthreads();   // F_t ready

    // ---- stage B: 12 x ds_read_b128 from own row h, packed rational ----
    const v2f E2  = {E0, E1};
    const v2f one = {1.f, 1.f};
    v2f acc2 = {0.f, 0.f};
    const float4* frow = (const float4*)(F_t + h * FSTRIDE);
    #pragma unroll
    for (int jq = 0; jq < NV / 4; ++jq) {
        const float4 f = frow[jq];       // 4 F values in one LDS instr
        const v2f t0 = __builtin_elementwise_fma(E2, (v2f){f.x, f.x}, one);
        const v2f t1 = __builtin_elementwise_fma(E2, (v2f){f.y, f.y}, one);
        const v2f t2 = __builtin_elementwise_fma(E2, (v2f){f.z, f.z}, one);
        const v2f t3 = __builtin_elementwise_fma(E2, (v2f){f.w, f.w}, one);
        const v2f p01 = t0 * t1, p23 = t2 * t3;
        const v2f num = __builtin_elementwise_fma(t0 + t1, p23, (t2 + t3) * p01);
        const v2f den = p01 * p23;
        v2f r;
        r.x = __builtin_amdgcn_rcpf(den.x);
        r.y = __builtin_amdgcn_rcpf(den.y);
        acc2 = __builtin_elementwise_fma(num, r, acc2);
    }

    // ---- epilogue ----
    const int nvalid = __popcll(bits);
    const float rden = __builtin_amdgcn_rcpf((float)nvalid);
    float* ob = out + (size_t)b * (NV * H);
    ob[r0 * H + h] = ((bits >> r0) & 1ull) ? acc2.x * rden : 0.0f;
    ob[r1 * H + h] = ((bits >> r1) & 1ull) ? acc2.y * rden : 0.0f;
}

extern "C" void kernel_launch(void* const* d_in, const int* in_sizes, int n_in,
                              void* d_out, int out_size, void* d_ws, size_t ws_size,
                              hipStream_t stream) {
    const float* z    = (const float*)d_in[0];
    const float* Wc   = (const float*)d_in[1];
    const float* bc   = (const float*)d_in[2];
    const float* Wy   = (const float*)d_in[3];
    const float* by   = (const float*)d_in[4];
    const int*   mask = (const int*)d_in[5];
    float* out = (float*)d_out;

    const int ngraph = in_sizes[0] / (NV * H);   // 512
    OptLinker_attn_kernel<<<ngraph, BLOCK, 0, stream>>>(z, Wc, bc, Wy, by, mask, out);
}